// Round 3
// baseline (235.271 us; speedup 1.0000x reference)
//
#include <hip/hip_runtime.h>
#include <math.h>

#define BB 8
#define SS 2048
#define NTOK (BB * SS)   // 16384

using bf16x8 = __attribute__((ext_vector_type(8))) short;
using f32x4  = __attribute__((ext_vector_type(4))) float;

__device__ __forceinline__ float gelu_tanh(float x) {
    float y = 0.7978845608f * (x + 0.044715f * x * x * x);
    float e = __expf(2.0f * y);
    float t = 1.0f - 2.0f / (e + 1.0f);
    return 0.5f * x * (1.0f + t);
}
__device__ __forceinline__ unsigned short f2b(float f) {
    unsigned int u = __float_as_uint(f);
    u += 0x7FFFu + ((u >> 16) & 1u);
    return (unsigned short)(u >> 16);
}
__device__ __forceinline__ float b2f(unsigned short u) {
    return __uint_as_float((unsigned int)u << 16);
}
__device__ __forceinline__ bf16x8 ldg_f32_b8(const float* p) {
    float4 f0 = *(const float4*)p, f1 = *(const float4*)(p + 4);
    union { ushort4 u[2]; bf16x8 v; } r;
    r.u[0] = (ushort4){f2b(f0.x), f2b(f0.y), f2b(f0.z), f2b(f0.w)};
    r.u[1] = (ushort4){f2b(f1.x), f2b(f1.y), f2b(f1.z), f2b(f1.w)};
    return r.v;
}

// ---------------------------------------------------------------------------
// Phase 1 (grid 512 x 512thr): bx<256 win_block (8-wave split of one window)
//                              bx>=256 stproj 128 rows (+ folded convW/Mf0).
// Exactly 512 blocks @ 2 blocks/CU (LDS 73.7KB) -> one round, 16 waves/CU.
// NOTE: no min-waves hint -- __launch_bounds__(256,2) regressed 2x (R1).
// ---------------------------------------------------------------------------
__global__ __launch_bounds__(512) void phase1(
    const float* __restrict__ x,
    const float* __restrict__ lw_in_w, const float* __restrict__ b_in,
    const float* __restrict__ lw_out_w, const float* __restrict__ b_out,
    const float* __restrict__ lng, const float* __restrict__ lnb,
    float* __restrict__ x1, unsigned short* __restrict__ x1b,
    const float* __restrict__ ffn_w1, const float* __restrict__ ffn_w2,
    unsigned short* __restrict__ Wb,
    const float* __restrict__ int_in_w, const float* __restrict__ int_out_w,
    unsigned short* __restrict__ Wib, unsigned short* __restrict__ Wiob,
    float* __restrict__ Mf,
    const float* __restrict__ spatial, const float* __restrict__ temporal,
    const float* __restrict__ spat_w, const float* __restrict__ temp_w,
    const float* __restrict__ bsp, const float* __restrict__ btp,
    unsigned short* __restrict__ snb, unsigned short* __restrict__ tnb,
    unsigned short* __restrict__ seb, unsigned short* __restrict__ teb)
{
    __shared__ unsigned short Qs[64 * 136];   // Q; attn-out in-place
    __shared__ unsigned short Ks[64 * 136];
    __shared__ unsigned short Vt[128 * 72];
    __shared__ unsigned short Pb[8][16 * 72]; // per-wave P (16 rows)
    __shared__ float red[2][128][2];
    const int tid = threadIdx.x;
    const int wv = tid >> 6, lane = tid & 63, ln = lane & 15, q = lane >> 4;

    if (blockIdx.x >= 256) {   // ---- stproj role (+ convW / Mf-zero fold) ----
        const int sidx = blockIdx.x - 256;      // 0..255
        if (sidx < 96) {                        // convW: 49152 float4 units
            int v = sidx * 512 + tid;
            const float* src; unsigned short* dst; int off;
            if (v < 16384)      { src = ffn_w1;    dst = Wb;         off = v; }
            else if (v < 32768) { src = ffn_w2;    dst = Wb + 65536; off = v - 16384; }
            else if (v < 45056) { src = int_in_w;  dst = Wib;        off = v - 32768; }
            else                { src = int_out_w; dst = Wiob;       off = v - 45056; }
            float4 f = *(const float4*)(src + (size_t)off * 4);
            *(ushort4*)(dst + (size_t)off * 4) =
                (ushort4){f2b(f.x), f2b(f.y), f2b(f.z), f2b(f.w)};
        } else if (sidx < 160) {                // Mf zero: 32768 float4 units
            int gt = (sidx - 96) * 512 + tid;
            *(float4*)(Mf + (size_t)gt * 4) = (float4){0.f, 0.f, 0.f, 0.f};
        }
        const int y = sidx >> 7;
        const int m0 = (sidx & 127) * 128;
        const float* Af = y ? temporal : spatial;
        const float* Wf = y ? temp_w : spat_w;
        const float* bias = y ? btp : bsp;
        unsigned short* nb = y ? tnb : snb;
        unsigned short* raw = y ? teb : seb;
        // two parallel 64-row sub-units: sub = wv>>2, w4 = wv&3
        const int sub = wv >> 2, w4 = wv & 3;
        const int wm = (w4 >> 1) * 32, wn = (w4 & 1) * 64;
        const int r0 = m0 + sub * 64;

        f32x4 acc[2][4] = {};
        #pragma unroll
        for (int kf = 0; kf < 4; ++kf) {
            bf16x8 a[2], b[4];
            #pragma unroll
            for (int fm = 0; fm < 2; ++fm)
                a[fm] = ldg_f32_b8(Af + (size_t)(r0 + wm + fm * 16 + ln) * 128 + kf * 32 + q * 8);
            #pragma unroll
            for (int fn = 0; fn < 4; ++fn)
                b[fn] = ldg_f32_b8(Wf + (size_t)(wn + fn * 16 + ln) * 128 + kf * 32 + q * 8);
            #pragma unroll
            for (int fm = 0; fm < 2; ++fm)
                #pragma unroll
                for (int fn = 0; fn < 4; ++fn)
                    acc[fm][fn] = __builtin_amdgcn_mfma_f32_16x16x32_bf16(a[fm], b[fn], acc[fm][fn], 0, 0, 0);
        }
        #pragma unroll
        for (int fm = 0; fm < 2; ++fm)
            #pragma unroll
            for (int r = 0; r < 4; ++r) {
                int rlg = sub * 64 + wm + fm * 16 + q * 4 + r;
                float s2 = 0.0f;
                #pragma unroll
                for (int fn = 0; fn < 4; ++fn) {
                    int col = wn + fn * 16 + ln;
                    float vv = acc[fm][fn][r] + bias[col];
                    acc[fm][fn][r] = vv;
                    s2 += vv * vv;
                }
                #pragma unroll
                for (int off = 1; off < 16; off <<= 1) s2 += __shfl_xor(s2, off, 64);
                if (ln == 0) red[0][rlg][w4 & 1] = s2;
            }
        __syncthreads();
        #pragma unroll
        for (int fm = 0; fm < 2; ++fm)
            #pragma unroll
            for (int r = 0; r < 4; ++r) {
                int rlg = sub * 64 + wm + fm * 16 + q * 4 + r;
                int row = m0 + rlg;
                float inv = 1.0f / fmaxf(sqrtf(red[0][rlg][0] + red[0][rlg][1]), 1e-8f);
                #pragma unroll
                for (int fn = 0; fn < 4; ++fn) {
                    int col = wn + fn * 16 + ln;
                    float vv = acc[fm][fn][r];
                    nb[(size_t)row * 128 + col] = f2b(vv * inv);
                    raw[(size_t)row * 128 + col] = f2b(vv);
                }
            }
        return;
    }

    // ---- win_block role: one 64-token window, 8 waves ----
    const int m0 = blockIdx.x * 64;
    const int wm4 = (wv >> 1) * 16, wn = (wv & 1) * 64;

    bf16x8 afr[4];
    #pragma unroll
    for (int kf = 0; kf < 4; ++kf)
        afr[kf] = ldg_f32_b8(x + (size_t)(m0 + wm4 + ln) * 128 + kf * 32 + q * 8);

    #pragma unroll
    for (int p = 0; p < 3; ++p) {
        f32x4 acc[4] = {};
        #pragma unroll
        for (int kf = 0; kf < 4; ++kf) {
            bf16x8 b[4];
            #pragma unroll
            for (int fn = 0; fn < 4; ++fn)
                b[fn] = ldg_f32_b8(lw_in_w + (size_t)(p * 128 + wn + fn * 16 + ln) * 128 + kf * 32 + q * 8);
            #pragma unroll
            for (int fn = 0; fn < 4; ++fn)
                acc[fn] = __builtin_amdgcn_mfma_f32_16x16x32_bf16(afr[kf], b[fn], acc[fn], 0, 0, 0);
        }
        #pragma unroll
        for (int r = 0; r < 4; ++r) {
            int rl = wm4 + q * 4 + r;
            #pragma unroll
            for (int fn = 0; fn < 4; ++fn) {
                int col = wn + fn * 16 + ln;
                unsigned short v = f2b(acc[fn][r] + b_in[p * 128 + col]);
                if (p == 0)      Qs[rl * 136 + col] = v;
                else if (p == 1) Ks[rl * 136 + col] = v;
                else             Vt[col * 72 + rl] = v;
            }
        }
    }
    __syncthreads();

    {   // ---- MFMA attention: wave = (16 q-rows) x (4 heads) ----
        const int mh3 = wv >> 1, hq = wv & 1;
        unsigned short* P = &Pb[wv][0];
        #pragma unroll
        for (int hh = 0; hh < 4; ++hh) {
            const int h = hq * 4 + hh;
            f32x4 sacc[4] = {};
            bf16x8 az = {}, bz[4] = {};
            if (q < 2) {
                az = *(const bf16x8*)&Qs[(mh3 * 16 + ln) * 136 + h * 16 + q * 8];
                #pragma unroll
                for (int fn = 0; fn < 4; ++fn)
                    bz[fn] = *(const bf16x8*)&Ks[(fn * 16 + ln) * 136 + h * 16 + q * 8];
            }
            #pragma unroll
            for (int fn = 0; fn < 4; ++fn)
                sacc[fn] = __builtin_amdgcn_mfma_f32_16x16x32_bf16(az, bz[fn], sacc[fn], 0, 0, 0);
            float invr[4];
            #pragma unroll
            for (int r = 0; r < 4; ++r) {
                int gi = mh3 * 16 + q * 4 + r;
                float mx = -1e30f;
                #pragma unroll
                for (int fn = 0; fn < 4; ++fn) {
                    int j = fn * 16 + ln;
                    float s = sacc[fn][r] * 0.25f;
                    if (j > gi) s = -1e30f;
                    sacc[fn][r] = s;
                    mx = fmaxf(mx, s);
                }
                #pragma unroll
                for (int off = 1; off < 16; off <<= 1)
                    mx = fmaxf(mx, __shfl_xor(mx, off, 64));
                float sum = 0.0f;
                #pragma unroll
                for (int fn = 0; fn < 4; ++fn) {
                    float p_ = __expf(sacc[fn][r] - mx);
                    sacc[fn][r] = p_;
                    sum += p_;
                }
                #pragma unroll
                for (int off = 1; off < 16; off <<= 1)
                    sum += __shfl_xor(sum, off, 64);
                invr[r] = 1.0f / sum;
                #pragma unroll
                for (int fn = 0; fn < 4; ++fn)
                    P[(q * 4 + r) * 72 + fn * 16 + ln] = f2b(sacc[fn][r]);
            }
            f32x4 oacc = {};
            #pragma unroll
            for (int kf2 = 0; kf2 < 2; ++kf2) {
                bf16x8 pa = *(const bf16x8*)&P[ln * 72 + kf2 * 32 + q * 8];
                bf16x8 vb = *(const bf16x8*)&Vt[(h * 16 + ln) * 72 + kf2 * 32 + q * 8];
                oacc = __builtin_amdgcn_mfma_f32_16x16x32_bf16(pa, vb, oacc, 0, 0, 0);
            }
            #pragma unroll
            for (int r = 0; r < 4; ++r)
                Qs[(mh3 * 16 + q * 4 + r) * 136 + h * 16 + ln] = f2b(oacc[r] * invr[r]);
        }
    }
    __syncthreads();

    // ---- out-proj + residual(x) + LN1 ----
    f32x4 acc[4] = {};
    #pragma unroll
    for (int kf = 0; kf < 4; ++kf) {
        bf16x8 a = *(const bf16x8*)&Qs[(wm4 + ln) * 136 + kf * 32 + q * 8];
        bf16x8 b[4];
        #pragma unroll
        for (int fn = 0; fn < 4; ++fn)
            b[fn] = ldg_f32_b8(lw_out_w + (size_t)(wn + fn * 16 + ln) * 128 + kf * 32 + q * 8);
        #pragma unroll
        for (int fn = 0; fn < 4; ++fn)
            acc[fn] = __builtin_amdgcn_mfma_f32_16x16x32_bf16(a, b[fn], acc[fn], 0, 0, 0);
    }
    #pragma unroll
    for (int r = 0; r < 4; ++r) {
        int rl = wm4 + q * 4 + r;
        int row = m0 + rl;
        float s1 = 0.0f, s2 = 0.0f;
        #pragma unroll
        for (int fn = 0; fn < 4; ++fn) {
            int col = wn + fn * 16 + ln;
            float vv = acc[fn][r] + b_out[col] + x[(size_t)row * 128 + col];
            acc[fn][r] = vv;
            s1 += vv; s2 += vv * vv;
        }
        #pragma unroll
        for (int off = 1; off < 16; off <<= 1) {
            s1 += __shfl_xor(s1, off, 64);
            s2 += __shfl_xor(s2, off, 64);
        }
        if (ln == 0) { red[0][rl][wv & 1] = s1; red[1][rl][wv & 1] = s2; }
    }
    __syncthreads();
    #pragma unroll
    for (int r = 0; r < 4; ++r) {
        int rl = wm4 + q * 4 + r;
        int row = m0 + rl;
        float mu = (red[0][rl][0] + red[0][rl][1]) * (1.0f / 128.0f);
        float var = (red[1][rl][0] + red[1][rl][1]) * (1.0f / 128.0f) - mu * mu;
        float rs = rsqrtf(var + 1e-5f);
        #pragma unroll
        for (int fn = 0; fn < 4; ++fn) {
            int col = wn + fn * 16 + ln;
            float o = (acc[fn][r] - mu) * rs * lng[col] + lnb[col];
            x1[(size_t)row * 128 + col] = o;
            x1b[(size_t)row * 128 + col] = f2b(o);
        }
    }
}

// ---------------------------------------------------------------------------
// Phase 2 (grid 768): bx<256 -> FFN, barrier-free: each wave owns 16 rows
// end-to-end (A-frags in regs, per-wave private H slice -- same wave-local
// LDS write->read pattern as phase1's Pb); bx>=256 -> atb split-K + atomics.
// ---------------------------------------------------------------------------
__global__ __launch_bounds__(256) void phase2(
    const unsigned short* __restrict__ x1b, const float* __restrict__ x1,
    const unsigned short* __restrict__ Wb,
    const float* __restrict__ b1, const float* __restrict__ b2,
    const float* __restrict__ lng, const float* __restrict__ lnb,
    float* __restrict__ x2,
    const unsigned short* __restrict__ snb, const unsigned short* __restrict__ tnb,
    float* __restrict__ Mf)
{
    __shared__ __align__(16) char pool[34816];
    const int tid = threadIdx.x;
    const int wv = tid >> 6, lane = tid & 63, ln = lane & 15, q = lane >> 4;

    if (blockIdx.x < 256) {   // ---- FFN role (zero barriers) ----
        unsigned short* Hw = (unsigned short*)pool + wv * 1152;  // [16][72] per wave
        const int t0 = blockIdx.x * 64;
        const int wm1 = wv * 16;
        const unsigned short* w1 = Wb;
        const unsigned short* w2 = Wb + 65536;

        bf16x8 afr[4];
        #pragma unroll
        for (int kf = 0; kf < 4; ++kf)
            afr[kf] = *(const bf16x8*)&x1b[(size_t)(t0 + wm1 + ln) * 128 + kf * 32 + q * 8];

        f32x4 acc2[8] = {};
        for (int ch = 0; ch < 8; ++ch) {
            const int hc0 = ch * 64;
            f32x4 acc1[4] = {};
            #pragma unroll
            for (int kf = 0; kf < 4; ++kf) {
                bf16x8 b[4];
                #pragma unroll
                for (int fn = 0; fn < 4; ++fn)
                    b[fn] = *(const bf16x8*)&w1[(size_t)(hc0 + fn * 16 + ln) * 128 + kf * 32 + q * 8];
                #pragma unroll
                for (int fn = 0; fn < 4; ++fn)
                    acc1[fn] = __builtin_amdgcn_mfma_f32_16x16x32_bf16(afr[kf], b[fn], acc1[fn], 0, 0, 0);
            }
            #pragma unroll
            for (int fn = 0; fn < 4; ++fn)
                #pragma unroll
                for (int r = 0; r < 4; ++r)
                    Hw[(q * 4 + r) * 72 + fn * 16 + ln] =
                        f2b(gelu_tanh(acc1[fn][r] + b1[hc0 + fn * 16 + ln]));
            #pragma unroll
            for (int kf2 = 0; kf2 < 2; ++kf2) {
                bf16x8 a = *(const bf16x8*)&Hw[ln * 72 + kf2 * 32 + q * 8];
                bf16x8 b8[8];
                #pragma unroll
                for (int fn = 0; fn < 8; ++fn)
                    b8[fn] = *(const bf16x8*)&w2[(size_t)(fn * 16 + ln) * 512 + hc0 + kf2 * 32 + q * 8];
                #pragma unroll
                for (int fn = 0; fn < 8; ++fn)
                    acc2[fn] = __builtin_amdgcn_mfma_f32_16x16x32_bf16(a, b8[fn], acc2[fn], 0, 0, 0);
            }
        }
        // epilogue: bias + residual + LN2, fully in-wave (128 cols per wave)
        #pragma unroll
        for (int r = 0; r < 4; ++r) {
            int row = t0 + wm1 + q * 4 + r;
            float s1 = 0.0f, s2 = 0.0f;
            #pragma unroll
            for (int fn = 0; fn < 8; ++fn) {
                int col = fn * 16 + ln;
                float vv = acc2[fn][r] + b2[col] + x1[(size_t)row * 128 + col];
                acc2[fn][r] = vv;
                s1 += vv; s2 += vv * vv;
            }
            #pragma unroll
            for (int off = 1; off < 16; off <<= 1) {
                s1 += __shfl_xor(s1, off, 64);
                s2 += __shfl_xor(s2, off, 64);
            }
            float mu = s1 * (1.0f / 128.0f);
            float var = s2 * (1.0f / 128.0f) - mu * mu;
            float rs = rsqrtf(var + 1e-5f);
            #pragma unroll
            for (int fn = 0; fn < 8; ++fn) {
                int col = fn * 16 + ln;
                x2[(size_t)row * 128 + col] = (acc2[fn][r] - mu) * rs * lng[col] + lnb[col];
            }
        }
        return;
    }

    // ---- atb split-K role (MFMA + fp32 atomics into Mf = M^T) ----
    {
        unsigned short* Sst = (unsigned short*)pool;            // [64 d][136 j-pitch]
        unsigned short* Tst = (unsigned short*)(pool + 17408);  // [64 e][136 j-pitch]
        const int idx2 = blockIdx.x - 256;     // 0..511
        const int d0 = (idx2 & 1) * 64, e0 = ((idx2 >> 1) & 1) * 64;
        const int z = idx2 >> 2;               // 0..127
        const int b = z >> 4, chunk = z & 15;
        const size_t rowb = (size_t)(b * SS + chunk * 128);

        #pragma unroll
        for (int it = 0; it < 4; ++it) {
            int j = (tid & 31) + it * 32;
            int c8 = (tid >> 5) * 8;
            uint4 sv = *(const uint4*)&snb[(rowb + j) * 128 + d0 + c8];
            uint4 tv = *(const uint4*)&tnb[(rowb + j) * 128 + e0 + c8];
            const unsigned short* sp = (const unsigned short*)&sv;
            const unsigned short* tp = (const unsigned short*)&tv;
            #pragma unroll
            for (int c = 0; c < 8; ++c) {
                Sst[(c8 + c) * 136 + j] = sp[c];
                Tst[(c8 + c) * 136 + j] = tp[c];
            }
        }
        __syncthreads();

        const int wm = (wv >> 1) * 32, wn = (wv & 1) * 32;
        f32x4 acc[2][2] = {};
        #pragma unroll
        for (int kf = 0; kf < 4; ++kf) {
            bf16x8 a[2], bb[2];
            #pragma unroll
            for (int fm = 0; fm < 2; ++fm)
                a[fm] = *(const bf16x8*)&Tst[(wm + fm * 16 + ln) * 136 + kf * 32 + q * 8];
            #pragma unroll
            for (int fn = 0; fn < 2; ++fn)
                bb[fn] = *(const bf16x8*)&Sst[(wn + fn * 16 + ln) * 136 + kf * 32 + q * 8];
            #pragma unroll
            for (int fm = 0; fm < 2; ++fm)
                #pragma unroll
                for (int fn = 0; fn < 2; ++fn)
                    acc[fm][fn] = __builtin_amdgcn_mfma_f32_16x16x32_bf16(a[fm], bb[fn], acc[fm][fn], 0, 0, 0);
        }
        float* pp = Mf + (size_t)b * 16384;
        #pragma unroll
        for (int fm = 0; fm < 2; ++fm)
            #pragma unroll
            for (int r = 0; r < 4; ++r) {
                int ee = e0 + wm + fm * 16 + q * 4 + r;
                #pragma unroll
                for (int fn = 0; fn < 2; ++fn) {
                    int dd = d0 + wn + fn * 16 + ln;
                    unsafeAtomicAdd(&pp[(size_t)ee * 128 + dd], acc[fm][fn][r]);
                }
            }
    }
}

// ---------------------------------------------------------------------------
// sim[row] = (1/S) <snb@M_b, tnb>_row via MFMA; M read fp32 from Mf (M^T).
// ---------------------------------------------------------------------------
__global__ __launch_bounds__(256) void simgemm_kernel(
    const unsigned short* __restrict__ snb, const unsigned short* __restrict__ tnb,
    const float* __restrict__ Mf, float* __restrict__ sim)
{
    __shared__ float red[64][2];
    const int tid = threadIdx.x, m0 = blockIdx.x * 64, b = m0 >> 11;
    const int wv = tid >> 6, lane = tid & 63, ln = lane & 15, q = lane >> 4;
    const int wm = (wv >> 1) * 32, wn = (wv & 1) * 64;

    f32x4 acc[2][4] = {};
    #pragma unroll
    for (int kf = 0; kf < 4; ++kf) {
        bf16x8 a[2], bb[4];
        #pragma unroll
        for (int fm = 0; fm < 2; ++fm)
            a[fm] = *(const bf16x8*)&snb[(size_t)(m0 + wm + fm * 16 + ln) * 128 + kf * 32 + q * 8];
        #pragma unroll
        for (int fn = 0; fn < 4; ++fn)
            bb[fn] = ldg_f32_b8(Mf + (size_t)b * 16384 + (size_t)(wn + fn * 16 + ln) * 128 + kf * 32 + q * 8);
        #pragma unroll
        for (int fm = 0; fm < 2; ++fm)
            #pragma unroll
            for (int fn = 0; fn < 4; ++fn)
                acc[fm][fn] = __builtin_amdgcn_mfma_f32_16x16x32_bf16(a[fm], bb[fn], acc[fm][fn], 0, 0, 0);
    }
    #pragma unroll
    for (int fm = 0; fm < 2; ++fm)
        #pragma unroll
        for (int r = 0; r < 4; ++r) {
            int rl = wm + fm * 16 + q * 4 + r;
            int row = m0 + rl;
            float s = 0.0f;
            #pragma unroll
            for (int fn = 0; fn < 4; ++fn) {
                int col = wn + fn * 16 + ln;
                s += acc[fm][fn][r] * b2f(tnb[(size_t)row * 128 + col]);
            }
            #pragma unroll
            for (int off = 1; off < 16; off <<= 1) s += __shfl_xor(s, off, 64);
            if (ln == 0) red[rl][wv & 1] = s;
        }
    __syncthreads();
    if (tid < 64) sim[m0 + tid] = (red[tid][0] + red[tid][1]) * (1.0f / (float)SS);
}

// ---------------------------------------------------------------------------
// Fused interaction block — weights pre-converted to bf16 (Wib/Wiob).
// ---------------------------------------------------------------------------
__global__ __launch_bounds__(256) void inter_block(
    const unsigned short* __restrict__ seb, const unsigned short* __restrict__ teb,
    const unsigned short* __restrict__ Wib,   // (384,128) bf16
    const float* __restrict__ b_int,
    const unsigned short* __restrict__ Wiob,  // (128,128) bf16
    const float* __restrict__ b_io,
    const float* __restrict__ sim, const float* __restrict__ x2,
    float* __restrict__ out)
{
    __shared__ unsigned short Qs[64 * 136];
    __shared__ unsigned short KVs[64 * 256];
    const int tid = threadIdx.x, s0 = blockIdx.x * 8;
    const int wv = tid >> 6, lane = tid & 63, ln = lane & 15, q = lane >> 4;
    const int wm = (wv >> 1) * 32, wn = (wv & 1) * 64;

    bf16x8 afr[4][2];
    #pragma unroll
    for (int kf = 0; kf < 4; ++kf)
        #pragma unroll
        for (int fm = 0; fm < 2; ++fm) {
            int rl = wm + fm * 16 + ln;
            size_t g = (size_t)(rl >> 3) * 2048 + s0 + (rl & 7);
            afr[kf][fm] = *(const bf16x8*)&seb[g * 128 + kf * 32 + q * 8];
        }

    #pragma unroll
    for (int p = 0; p < 3; ++p) {
        if (p == 1) {
            #pragma unroll
            for (int kf = 0; kf < 4; ++kf)
                #pragma unroll
                for (int fm = 0; fm < 2; ++fm) {
                    int rl = wm + fm * 16 + ln;
                    size_t g = (size_t)(rl >> 3) * 2048 + s0 + (rl & 7);
                    afr[kf][fm] = *(const bf16x8*)&teb[g * 128 + kf * 32 + q * 8];
                }
        }
        f32x4 acc[2][4] = {};
        #pragma unroll
        for (int kf = 0; kf < 4; ++kf) {
            bf16x8 b[4];
            #pragma unroll
            for (int fn = 0; fn < 4; ++fn)
                b[fn] = *(const bf16x8*)&Wib[(size_t)(p * 128 + wn + fn * 16 + ln) * 128 + kf * 32 + q * 8];
            #pragma unroll
            for (int fm = 0; fm < 2; ++fm)
                #pragma unroll
                for (int fn = 0; fn < 4; ++fn)
                    acc[fm][fn] = __builtin_amdgcn_mfma_f32_16x16x32_bf16(afr[kf][fm], b[fn], acc[fm][fn], 0, 0, 0);
        }
        #pragma unroll
        for (int fm = 0; fm < 2; ++fm)
            #pragma unroll
            for (int r = 0; r < 4; ++r) {
                int rl = wm + fm * 16 + q * 4 + r;
                #pragma unroll
                for (int fn = 0; fn < 4; ++fn) {
                    int col = wn + fn * 16 + ln;
                    unsigned short v = f2b(acc[fm][fn][r] + b_int[p * 128 + col]);
                    if (p == 0) Qs[rl * 136 + col] = v;
                    else        KVs[rl * 256 + (p - 1) * 128 + col] = v;
                }
            }
        __syncthreads();
    }

    #pragma unroll
    for (int tt = 0; tt < 2; ++tt) {
        int task = tid + tt * 256;
        int ss = task >> 6, h = (task >> 3) & 7, i = task & 7;
        int rq = i * 8 + ss;
        float qr[16];
        {
            uint4 q0 = *(const uint4*)&Qs[rq * 136 + h * 16];
            uint4 q1 = *(const uint4*)&Qs[rq * 136 + h * 16 + 8];
            const unsigned short* p0 = (const unsigned short*)&q0;
            const unsigned short* p1 = (const unsigned short*)&q1;
            #pragma unroll
            for (int c = 0; c < 8; ++c) { qr[c] = b2f(p0[c]); qr[8 + c] = b2f(p1[c]); }
        }
        float sc[8];
        #pragma unroll
        for (int j = 0; j < 8; ++j) {
            uint4 k0 = *(const uint4*)&KVs[(j * 8 + ss) * 256 + h * 16];
            uint4 k1 = *(const uint4*)&KVs[(j * 8 + ss) * 256 + h * 16 + 8];
            const unsigned short* kp0 = (const unsigned short*)&k0;
            const unsigned short* kp1 = (const unsigned short*)&k1;
            float s = 0.0f;
            #pragma unroll
            for (int c = 0; c < 8; ++c) {
                s = fmaf(qr[c], b2f(kp0[c]), s);
                s = fmaf(qr[8 + c], b2f(kp1[c]), s);
            }
            sc[j] = s * 0.25f;
        }
        float mx = -1e30f;
        #pragma unroll
        for (int j = 0; j < 8; ++j) mx = fmaxf(mx, sc[j]);
        float pe[8], se = 0.0f;
        #pragma unroll
        for (int j = 0; j < 8; ++j) { pe[j] = __expf(sc[j] - mx); se += pe[j]; }
        float inv = 1.0f / se;
        float o[16] = {};
        #pragma unroll
        for (int j = 0; j < 8; ++j) {
            uint4 v0 = *(const uint4*)&KVs[(j * 8 + ss) * 256 + 128 + h * 16];
            uint4 v1 = *(const uint4*)&KVs[(j * 8 + ss) * 256 + 128 + h * 16 + 8];
            const unsigned short* vp0 = (const unsigned short*)&v0;
            const unsigned short* vp1 = (const unsigned short*)&v1;
            #pragma unroll
            for (int c = 0; c < 8; ++c) {
                o[c]     += pe[j] * b2f(vp0[c]);
                o[8 + c] += pe[j] * b2f(vp1[c]);
            }
        }
        ushort4 w0 = (ushort4){f2b(o[0]*inv),  f2b(o[1]*inv),  f2b(o[2]*inv),  f2b(o[3]*inv)};
        ushort4 w1 = (ushort4){f2b(o[4]*inv),  f2b(o[5]*inv),  f2b(o[6]*inv),  f2b(o[7]*inv)};
        ushort4 w2 = (ushort4){f2b(o[8]*inv),  f2b(o[9]*inv),  f2b(o[10]*inv), f2b(o[11]*inv)};
        ushort4 w3 = (ushort4){f2b(o[12]*inv), f2b(o[13]*inv), f2b(o[14]*inv), f2b(o[15]*inv)};
        *(ushort4*)&Qs[rq * 136 + h * 16]      = w0;
        *(ushort4*)&Qs[rq * 136 + h * 16 + 4]  = w1;
        *(ushort4*)&Qs[rq * 136 + h * 16 + 8]  = w2;
        *(ushort4*)&Qs[rq * 136 + h * 16 + 12] = w3;
    }
    __syncthreads();

    f32x4 acc[2][4] = {};
    #pragma unroll
    for (int kf = 0; kf < 4; ++kf) {
        bf16x8 a[2], b[4];
        #pragma unroll
        for (int fm = 0; fm < 2; ++fm)
            a[fm] = *(const bf16x8*)&Qs[(wm + fm * 16 + ln) * 136 + kf * 32 + q * 8];
        #pragma unroll
        for (int fn = 0; fn < 4; ++fn)
            b[fn] = *(const bf16x8*)&Wiob[(size_t)(wn + fn * 16 + ln) * 128 + kf * 32 + q * 8];
        #pragma unroll
        for (int fm = 0; fm < 2; ++fm)
            #pragma unroll
            for (int fn = 0; fn < 4; ++fn)
                acc[fm][fn] = __builtin_amdgcn_mfma_f32_16x16x32_bf16(a[fm], b[fn], acc[fm][fn], 0, 0, 0);
    }
    #pragma unroll
    for (int fm = 0; fm < 2; ++fm)
        #pragma unroll
        for (int r = 0; r < 4; ++r) {
            int rl = wm + fm * 16 + q * 4 + r;
            size_t g = (size_t)(rl >> 3) * 2048 + s0 + (rl & 7);
            float sc = sim[g];
            #pragma unroll
            for (int fn = 0; fn < 4; ++fn) {
                int col = wn + fn * 16 + ln;
                out[g * 128 + col] = (acc[fm][fn][r] + b_io[col]) * sc + x2[g * 128 + col];
            }
        }
}

// ---------------------------------------------------------------------------
extern "C" void kernel_launch(void* const* d_in, const int* in_sizes, int n_in,
                              void* d_out, int out_size, void* d_ws, size_t ws_size,
                              hipStream_t stream)
{
    const float* x        = (const float*)d_in[0];
    const float* spatial  = (const float*)d_in[1];
    const float* temporal = (const float*)d_in[2];
    const float* lw_in_w  = (const float*)d_in[3];
    const float* lw_in_b  = (const float*)d_in[4];
    const float* lw_out_w = (const float*)d_in[5];
    const float* lw_out_b = (const float*)d_in[6];
    const float* spat_w   = (const float*)d_in[7];
    const float* spat_b   = (const float*)d_in[8];
    const float* temp_w   = (const float*)d_in[9];
    const float* temp_b   = (const float*)d_in[10];
    const float* int_in_w = (const float*)d_in[11];
    const float* int_in_b = (const float*)d_in[12];
    const float* int_out_w= (const float*)d_in[13];
    const float* int_out_b= (const float*)d_in[14];
    const float* ffn_b1   = (const float*)d_in[16];
    const float* ffn_b2   = (const float*)d_in[18];
    const float* ln1_g    = (const float*)d_in[19];
    const float* ln1_b    = (const float*)d_in[20];
    const float* ln2_g    = (const float*)d_in[21];
    const float* ln2_b    = (const float*)d_in[22];
    float* out = (float*)d_out;

    // ---- workspace layout (bytes) ----
    char* base = (char*)d_ws;
    float*          x1   = (float*)(base + 0);                   // 8,388,608
    unsigned short* x1b  = (unsigned short*)(base + 8388608);    // 4,194,304
    float*          x2   = (float*)(base + 12582912);            // 8,388,608
    unsigned short* snb  = (unsigned short*)(base + 20971520);   // 4,194,304
    unsigned short* tnb  = (unsigned short*)(base + 25165824);   // 4,194,304
    unsigned short* seb  = (unsigned short*)(base + 29360128);   // 4,194,304
    unsigned short* teb  = (unsigned short*)(base + 33554432);   // 4,194,304
    unsigned short* Wb   = (unsigned short*)(base + 37748736);   //   262,144
    unsigned short* Wib  = (unsigned short*)(base + 38010880);   //    98,304
    unsigned short* Wiob = (unsigned short*)(base + 38109184);   //    32,768
    float*          Mf   = (float*)(base + 38141952);            //   524,288
    float*          simb = (float*)(base + 38666240);            //    65,536

    // 1: win_block (256, 8-wave) + stproj/convW/Mf0 (256) -- 512x512thr
    phase1<<<512, 512, 0, stream>>>(
        x, lw_in_w, lw_in_b, lw_out_w, lw_out_b, ln1_g, ln1_b, x1, x1b,
        (const float*)d_in[15], (const float*)d_in[17], Wb,
        int_in_w, int_out_w, Wib, Wiob, Mf,
        spatial, temporal, spat_w, temp_w, spat_b, temp_b,
        snb, tnb, seb, teb);
    // 2: ffn barrier-free (256) + atb split-K with fp32 atomics into Mf (512)
    phase2<<<768, 256, 0, stream>>>(
        x1b, x1, Wb, ffn_b1, ffn_b2, ln2_g, ln2_b, x2, snb, tnb, Mf);
    // 3: sim via MFMA (reads Mf fp32)
    simgemm_kernel<<<256, 256, 0, stream>>>(snb, tnb, Mf, simb);
    // 4: interaction block (bf16 weights)
    inter_block<<<256, 256, 0, stream>>>(
        seb, teb, Wib, int_in_b, Wiob, int_out_b, simb, x2, out);
}

// Round 4
// 209.085 us; speedup vs baseline: 1.1252x; 1.1252x over previous
//
#include <hip/hip_runtime.h>
#include <math.h>

#define BB 8
#define SS 2048
#define NTOK (BB * SS)   // 16384

using bf16x8 = __attribute__((ext_vector_type(8))) short;
using f32x4  = __attribute__((ext_vector_type(4))) float;

__device__ __forceinline__ float gelu_tanh(float x) {
    float y = 0.7978845608f * (x + 0.044715f * x * x * x);
    float e = __expf(2.0f * y);
    float t = 1.0f - 2.0f / (e + 1.0f);
    return 0.5f * x * (1.0f + t);
}
__device__ __forceinline__ unsigned short f2b(float f) {
    unsigned int u = __float_as_uint(f);
    u += 0x7FFFu + ((u >> 16) & 1u);
    return (unsigned short)(u >> 16);
}
__device__ __forceinline__ float b2f(unsigned short u) {
    return __uint_as_float((unsigned int)u << 16);
}
__device__ __forceinline__ bf16x8 ldg_f32_b8(const float* p) {
    float4 f0 = *(const float4*)p, f1 = *(const float4*)(p + 4);
    union { ushort4 u[2]; bf16x8 v; } r;
    r.u[0] = (ushort4){f2b(f0.x), f2b(f0.y), f2b(f0.z), f2b(f0.w)};
    r.u[1] = (ushort4){f2b(f1.x), f2b(f1.y), f2b(f1.z), f2b(f1.w)};
    return r.v;
}

// ---------------------------------------------------------------------------
// Phase 0 (grid 416 x 256): convert ALL weight matrices f32->bf16 + zero Mf.
// One float4 unit per thread. ~3-4 us; removes ~64 convert-ops per wave from
// phase1's serial chain.
// ---------------------------------------------------------------------------
__global__ __launch_bounds__(256) void phase0(
    const float* __restrict__ lw_in_w, const float* __restrict__ lw_out_w,
    const float* __restrict__ spat_w, const float* __restrict__ temp_w,
    const float* __restrict__ ffn_w1, const float* __restrict__ ffn_w2,
    const float* __restrict__ int_in_w, const float* __restrict__ int_out_w,
    unsigned short* __restrict__ Wlwb, unsigned short* __restrict__ Wstb,
    unsigned short* __restrict__ Wb,
    unsigned short* __restrict__ Wib, unsigned short* __restrict__ Wiob,
    float* __restrict__ Mf)
{
    int v = blockIdx.x * 256 + threadIdx.x;   // 0..106495 float4 units
    if (v < 73728) {
        const float* src; unsigned short* dst; int off;
        if (v < 12288)      { src = lw_in_w;   dst = Wlwb;          off = v; }
        else if (v < 16384) { src = lw_out_w;  dst = Wlwb + 49152;  off = v - 12288; }
        else if (v < 20480) { src = spat_w;    dst = Wstb;          off = v - 16384; }
        else if (v < 24576) { src = temp_w;    dst = Wstb + 16384;  off = v - 20480; }
        else if (v < 40960) { src = ffn_w1;    dst = Wb;            off = v - 24576; }
        else if (v < 57344) { src = ffn_w2;    dst = Wb + 65536;    off = v - 40960; }
        else if (v < 69632) { src = int_in_w;  dst = Wib;           off = v - 57344; }
        else                { src = int_out_w; dst = Wiob;          off = v - 69632; }
        float4 f = *(const float4*)(src + (size_t)off * 4);
        *(ushort4*)(dst + (size_t)off * 4) =
            (ushort4){f2b(f.x), f2b(f.y), f2b(f.z), f2b(f.w)};
    } else {
        *(float4*)(Mf + (size_t)(v - 73728) * 4) = (float4){0.f, 0.f, 0.f, 0.f};
    }
}

// ---------------------------------------------------------------------------
// Phase 1 (grid 768 x 256): bx<256 win_block | bx>=256 stproj (64 rows).
// R2 geometry (4-wave win): 512-thr / 8-wave variant regressed (R3, VGPR 68);
// min-waves hints regress (R1). Weights read pre-converted bf16 (phase0).
// ---------------------------------------------------------------------------
__global__ __launch_bounds__(256) void phase1(
    const float* __restrict__ x,
    const unsigned short* __restrict__ lwinb,   // (384,128) bf16
    const float* __restrict__ b_in,
    const unsigned short* __restrict__ lwoutb,  // (128,128) bf16
    const float* __restrict__ b_out,
    const float* __restrict__ lng, const float* __restrict__ lnb,
    float* __restrict__ x1, unsigned short* __restrict__ x1b,
    const float* __restrict__ spatial, const float* __restrict__ temporal,
    const unsigned short* __restrict__ spwb, const unsigned short* __restrict__ tpwb,
    const float* __restrict__ bsp, const float* __restrict__ btp,
    unsigned short* __restrict__ snb, unsigned short* __restrict__ tnb,
    unsigned short* __restrict__ seb, unsigned short* __restrict__ teb)
{
    __shared__ unsigned short Qs[64 * 136];   // Q; attn-out in-place
    __shared__ unsigned short Ks[64 * 136];
    __shared__ unsigned short Vt[128 * 72];
    __shared__ unsigned short Pb[4][32 * 72];
    __shared__ float red[2][64][2];
    const int tid = threadIdx.x;
    const int wv = tid >> 6, lane = tid & 63, ln = lane & 15, q = lane >> 4;

    if (blockIdx.x >= 256) {   // ---- stproj role ----
        const int idx2 = blockIdx.x - 256;
        const int y = idx2 >> 8;
        const int m0 = (idx2 & 255) * 64;
        const float* Af = y ? temporal : spatial;
        const unsigned short* Wfb = y ? tpwb : spwb;
        const float* bias = y ? btp : bsp;
        unsigned short* nb = y ? tnb : snb;
        unsigned short* raw = y ? teb : seb;
        const int wm = (wv >> 1) * 32, wn = (wv & 1) * 64;

        f32x4 acc[2][4] = {};
        #pragma unroll
        for (int kf = 0; kf < 4; ++kf) {
            bf16x8 a[2], b[4];
            #pragma unroll
            for (int fm = 0; fm < 2; ++fm)
                a[fm] = ldg_f32_b8(Af + (size_t)(m0 + wm + fm * 16 + ln) * 128 + kf * 32 + q * 8);
            #pragma unroll
            for (int fn = 0; fn < 4; ++fn)
                b[fn] = *(const bf16x8*)&Wfb[(size_t)(wn + fn * 16 + ln) * 128 + kf * 32 + q * 8];
            #pragma unroll
            for (int fm = 0; fm < 2; ++fm)
                #pragma unroll
                for (int fn = 0; fn < 4; ++fn)
                    acc[fm][fn] = __builtin_amdgcn_mfma_f32_16x16x32_bf16(a[fm], b[fn], acc[fm][fn], 0, 0, 0);
        }
        #pragma unroll
        for (int fm = 0; fm < 2; ++fm)
            #pragma unroll
            for (int r = 0; r < 4; ++r) {
                int rl = wm + fm * 16 + q * 4 + r;
                float s2 = 0.0f;
                #pragma unroll
                for (int fn = 0; fn < 4; ++fn) {
                    int col = wn + fn * 16 + ln;
                    float vv = acc[fm][fn][r] + bias[col];
                    acc[fm][fn][r] = vv;
                    s2 += vv * vv;
                }
                #pragma unroll
                for (int off = 1; off < 16; off <<= 1) s2 += __shfl_xor(s2, off, 64);
                if (ln == 0) red[0][rl][wv & 1] = s2;
            }
        __syncthreads();
        #pragma unroll
        for (int fm = 0; fm < 2; ++fm)
            #pragma unroll
            for (int r = 0; r < 4; ++r) {
                int rl = wm + fm * 16 + q * 4 + r;
                int row = m0 + rl;
                float inv = 1.0f / fmaxf(sqrtf(red[0][rl][0] + red[0][rl][1]), 1e-8f);
                #pragma unroll
                for (int fn = 0; fn < 4; ++fn) {
                    int col = wn + fn * 16 + ln;
                    float vv = acc[fm][fn][r];
                    nb[(size_t)row * 128 + col] = f2b(vv * inv);
                    raw[(size_t)row * 128 + col] = f2b(vv);
                }
            }
        return;
    }

    // ---- win_block role ----
    const int m0 = blockIdx.x * 64;
    const int wm = (wv >> 1) * 32, wn = (wv & 1) * 64;

    bf16x8 afr[4][2];
    #pragma unroll
    for (int kf = 0; kf < 4; ++kf)
        #pragma unroll
        for (int fm = 0; fm < 2; ++fm)
            afr[kf][fm] = ldg_f32_b8(x + (size_t)(m0 + wm + fm * 16 + ln) * 128 + kf * 32 + q * 8);

    #pragma unroll
    for (int p = 0; p < 3; ++p) {
        f32x4 acc[2][4] = {};
        #pragma unroll
        for (int kf = 0; kf < 4; ++kf) {
            bf16x8 b[4];
            #pragma unroll
            for (int fn = 0; fn < 4; ++fn)
                b[fn] = *(const bf16x8*)&lwinb[(size_t)(p * 128 + wn + fn * 16 + ln) * 128 + kf * 32 + q * 8];
            #pragma unroll
            for (int fm = 0; fm < 2; ++fm)
                #pragma unroll
                for (int fn = 0; fn < 4; ++fn)
                    acc[fm][fn] = __builtin_amdgcn_mfma_f32_16x16x32_bf16(afr[kf][fm], b[fn], acc[fm][fn], 0, 0, 0);
        }
        #pragma unroll
        for (int fm = 0; fm < 2; ++fm)
            #pragma unroll
            for (int r = 0; r < 4; ++r) {
                int rl = wm + fm * 16 + q * 4 + r;
                #pragma unroll
                for (int fn = 0; fn < 4; ++fn) {
                    int col = wn + fn * 16 + ln;
                    unsigned short v = f2b(acc[fm][fn][r] + b_in[p * 128 + col]);
                    if (p == 0)      Qs[rl * 136 + col] = v;
                    else if (p == 1) Ks[rl * 136 + col] = v;
                    else             Vt[col * 72 + rl] = v;
                }
            }
    }
    __syncthreads();

    {   // ---- MFMA attention ----
        const int mh = wv >> 1, hq = wv & 1;
        unsigned short* P = &Pb[wv][0];
        #pragma unroll
        for (int hh = 0; hh < 4; ++hh) {
            const int h = hq * 4 + hh;
            f32x4 sacc[2][4] = {};
            bf16x8 az[2] = {}, bz[4] = {};
            if (q < 2) {
                #pragma unroll
                for (int fm = 0; fm < 2; ++fm)
                    az[fm] = *(const bf16x8*)&Qs[(mh * 32 + fm * 16 + ln) * 136 + h * 16 + q * 8];
                #pragma unroll
                for (int fn = 0; fn < 4; ++fn)
                    bz[fn] = *(const bf16x8*)&Ks[(fn * 16 + ln) * 136 + h * 16 + q * 8];
            }
            #pragma unroll
            for (int fm = 0; fm < 2; ++fm)
                #pragma unroll
                for (int fn = 0; fn < 4; ++fn)
                    sacc[fm][fn] = __builtin_amdgcn_mfma_f32_16x16x32_bf16(az[fm], bz[fn], sacc[fm][fn], 0, 0, 0);
            float invr[2][4];
            #pragma unroll
            for (int fm = 0; fm < 2; ++fm)
                #pragma unroll
                for (int r = 0; r < 4; ++r) {
                    int gi = mh * 32 + fm * 16 + q * 4 + r;
                    float mx = -1e30f;
                    #pragma unroll
                    for (int fn = 0; fn < 4; ++fn) {
                        int j = fn * 16 + ln;
                        float s = sacc[fm][fn][r] * 0.25f;
                        if (j > gi) s = -1e30f;
                        sacc[fm][fn][r] = s;
                        mx = fmaxf(mx, s);
                    }
                    #pragma unroll
                    for (int off = 1; off < 16; off <<= 1)
                        mx = fmaxf(mx, __shfl_xor(mx, off, 64));
                    float sum = 0.0f;
                    #pragma unroll
                    for (int fn = 0; fn < 4; ++fn) {
                        float p_ = __expf(sacc[fm][fn][r] - mx);
                        sacc[fm][fn][r] = p_;
                        sum += p_;
                    }
                    #pragma unroll
                    for (int off = 1; off < 16; off <<= 1)
                        sum += __shfl_xor(sum, off, 64);
                    invr[fm][r] = 1.0f / sum;
                    #pragma unroll
                    for (int fn = 0; fn < 4; ++fn)
                        P[(fm * 16 + q * 4 + r) * 72 + fn * 16 + ln] = f2b(sacc[fm][fn][r]);
                }
            f32x4 oacc[2] = {};
            #pragma unroll
            for (int kf2 = 0; kf2 < 2; ++kf2) {
                bf16x8 pa[2], vb;
                #pragma unroll
                for (int fm = 0; fm < 2; ++fm)
                    pa[fm] = *(const bf16x8*)&P[(fm * 16 + ln) * 72 + kf2 * 32 + q * 8];
                vb = *(const bf16x8*)&Vt[(h * 16 + ln) * 72 + kf2 * 32 + q * 8];
                #pragma unroll
                for (int fm = 0; fm < 2; ++fm)
                    oacc[fm] = __builtin_amdgcn_mfma_f32_16x16x32_bf16(pa[fm], vb, oacc[fm], 0, 0, 0);
            }
            #pragma unroll
            for (int fm = 0; fm < 2; ++fm)
                #pragma unroll
                for (int r = 0; r < 4; ++r)
                    Qs[(mh * 32 + fm * 16 + q * 4 + r) * 136 + h * 16 + ln] =
                        f2b(oacc[fm][r] * invr[fm][r]);
        }
    }
    __syncthreads();

    // ---- out-proj + residual(x) + LN1 ----
    f32x4 acc[2][4] = {};
    #pragma unroll
    for (int kf = 0; kf < 4; ++kf) {
        bf16x8 a[2], b[4];
        #pragma unroll
        for (int fm = 0; fm < 2; ++fm)
            a[fm] = *(const bf16x8*)&Qs[(wm + fm * 16 + ln) * 136 + kf * 32 + q * 8];
        #pragma unroll
        for (int fn = 0; fn < 4; ++fn)
            b[fn] = *(const bf16x8*)&lwoutb[(size_t)(wn + fn * 16 + ln) * 128 + kf * 32 + q * 8];
        #pragma unroll
        for (int fm = 0; fm < 2; ++fm)
            #pragma unroll
            for (int fn = 0; fn < 4; ++fn)
                acc[fm][fn] = __builtin_amdgcn_mfma_f32_16x16x32_bf16(a[fm], b[fn], acc[fm][fn], 0, 0, 0);
    }
    #pragma unroll
    for (int fm = 0; fm < 2; ++fm)
        #pragma unroll
        for (int r = 0; r < 4; ++r) {
            int rl = wm + fm * 16 + q * 4 + r;
            int row = m0 + rl;
            float s1 = 0.0f, s2 = 0.0f;
            #pragma unroll
            for (int fn = 0; fn < 4; ++fn) {
                int col = wn + fn * 16 + ln;
                float vv = acc[fm][fn][r] + b_out[col] + x[(size_t)row * 128 + col];
                acc[fm][fn][r] = vv;
                s1 += vv; s2 += vv * vv;
            }
            #pragma unroll
            for (int off = 1; off < 16; off <<= 1) {
                s1 += __shfl_xor(s1, off, 64);
                s2 += __shfl_xor(s2, off, 64);
            }
            if (ln == 0) { red[0][rl][wv & 1] = s1; red[1][rl][wv & 1] = s2; }
        }
    __syncthreads();
    #pragma unroll
    for (int fm = 0; fm < 2; ++fm)
        #pragma unroll
        for (int r = 0; r < 4; ++r) {
            int rl = wm + fm * 16 + q * 4 + r;
            int row = m0 + rl;
            float mu = (red[0][rl][0] + red[0][rl][1]) * (1.0f / 128.0f);
            float var = (red[1][rl][0] + red[1][rl][1]) * (1.0f / 128.0f) - mu * mu;
            float rs = rsqrtf(var + 1e-5f);
            #pragma unroll
            for (int fn = 0; fn < 4; ++fn) {
                int col = wn + fn * 16 + ln;
                float o = (acc[fm][fn][r] - mu) * rs * lng[col] + lnb[col];
                x1[(size_t)row * 128 + col] = o;
                x1b[(size_t)row * 128 + col] = f2b(o);
            }
        }
}

// ---------------------------------------------------------------------------
// Phase 2 (grid 768): bx<256 -> FFN, barrier-free (wave-owns-16-rows);
// bx>=256 -> atb split-K with fp32 atomics into Mf (M^T layout).
// ---------------------------------------------------------------------------
__global__ __launch_bounds__(256) void phase2(
    const unsigned short* __restrict__ x1b, const float* __restrict__ x1,
    const unsigned short* __restrict__ Wb,
    const float* __restrict__ b1, const float* __restrict__ b2,
    const float* __restrict__ lng, const float* __restrict__ lnb,
    float* __restrict__ x2,
    const unsigned short* __restrict__ snb, const unsigned short* __restrict__ tnb,
    float* __restrict__ Mf)
{
    __shared__ __align__(16) char pool[34816];
    const int tid = threadIdx.x;
    const int wv = tid >> 6, lane = tid & 63, ln = lane & 15, q = lane >> 4;

    if (blockIdx.x < 256) {   // ---- FFN role (zero barriers) ----
        unsigned short* Hw = (unsigned short*)pool + wv * 1152;  // [16][72] per wave
        const int t0 = blockIdx.x * 64;
        const int wm1 = wv * 16;
        const unsigned short* w1 = Wb;
        const unsigned short* w2 = Wb + 65536;

        bf16x8 afr[4];
        #pragma unroll
        for (int kf = 0; kf < 4; ++kf)
            afr[kf] = *(const bf16x8*)&x1b[(size_t)(t0 + wm1 + ln) * 128 + kf * 32 + q * 8];

        f32x4 acc2[8] = {};
        for (int ch = 0; ch < 8; ++ch) {
            const int hc0 = ch * 64;
            f32x4 acc1[4] = {};
            #pragma unroll
            for (int kf = 0; kf < 4; ++kf) {
                bf16x8 b[4];
                #pragma unroll
                for (int fn = 0; fn < 4; ++fn)
                    b[fn] = *(const bf16x8*)&w1[(size_t)(hc0 + fn * 16 + ln) * 128 + kf * 32 + q * 8];
                #pragma unroll
                for (int fn = 0; fn < 4; ++fn)
                    acc1[fn] = __builtin_amdgcn_mfma_f32_16x16x32_bf16(afr[kf], b[fn], acc1[fn], 0, 0, 0);
            }
            #pragma unroll
            for (int fn = 0; fn < 4; ++fn)
                #pragma unroll
                for (int r = 0; r < 4; ++r)
                    Hw[(q * 4 + r) * 72 + fn * 16 + ln] =
                        f2b(gelu_tanh(acc1[fn][r] + b1[hc0 + fn * 16 + ln]));
            #pragma unroll
            for (int kf2 = 0; kf2 < 2; ++kf2) {
                bf16x8 a = *(const bf16x8*)&Hw[ln * 72 + kf2 * 32 + q * 8];
                bf16x8 b8[8];
                #pragma unroll
                for (int fn = 0; fn < 8; ++fn)
                    b8[fn] = *(const bf16x8*)&w2[(size_t)(fn * 16 + ln) * 512 + hc0 + kf2 * 32 + q * 8];
                #pragma unroll
                for (int fn = 0; fn < 8; ++fn)
                    acc2[fn] = __builtin_amdgcn_mfma_f32_16x16x32_bf16(a, b8[fn], acc2[fn], 0, 0, 0);
            }
        }
        // epilogue: bias + residual + LN2, fully in-wave (128 cols per wave)
        #pragma unroll
        for (int r = 0; r < 4; ++r) {
            int row = t0 + wm1 + q * 4 + r;
            float s1 = 0.0f, s2 = 0.0f;
            #pragma unroll
            for (int fn = 0; fn < 8; ++fn) {
                int col = fn * 16 + ln;
                float vv = acc2[fn][r] + b2[col] + x1[(size_t)row * 128 + col];
                acc2[fn][r] = vv;
                s1 += vv; s2 += vv * vv;
            }
            #pragma unroll
            for (int off = 1; off < 16; off <<= 1) {
                s1 += __shfl_xor(s1, off, 64);
                s2 += __shfl_xor(s2, off, 64);
            }
            float mu = s1 * (1.0f / 128.0f);
            float var = s2 * (1.0f / 128.0f) - mu * mu;
            float rs = rsqrtf(var + 1e-5f);
            #pragma unroll
            for (int fn = 0; fn < 8; ++fn) {
                int col = fn * 16 + ln;
                x2[(size_t)row * 128 + col] = (acc2[fn][r] - mu) * rs * lng[col] + lnb[col];
            }
        }
        return;
    }

    // ---- atb split-K role (MFMA + fp32 atomics into Mf = M^T) ----
    {
        unsigned short* Sst = (unsigned short*)pool;            // [64 d][136 j-pitch]
        unsigned short* Tst = (unsigned short*)(pool + 17408);  // [64 e][136 j-pitch]
        const int idx2 = blockIdx.x - 256;     // 0..511
        const int d0 = (idx2 & 1) * 64, e0 = ((idx2 >> 1) & 1) * 64;
        const int z = idx2 >> 2;               // 0..127
        const int b = z >> 4, chunk = z & 15;
        const size_t rowb = (size_t)(b * SS + chunk * 128);

        #pragma unroll
        for (int it = 0; it < 4; ++it) {
            int j = (tid & 31) + it * 32;
            int c8 = (tid >> 5) * 8;
            uint4 sv = *(const uint4*)&snb[(rowb + j) * 128 + d0 + c8];
            uint4 tv = *(const uint4*)&tnb[(rowb + j) * 128 + e0 + c8];
            const unsigned short* sp = (const unsigned short*)&sv;
            const unsigned short* tp = (const unsigned short*)&tv;
            #pragma unroll
            for (int c = 0; c < 8; ++c) {
                Sst[(c8 + c) * 136 + j] = sp[c];
                Tst[(c8 + c) * 136 + j] = tp[c];
            }
        }
        __syncthreads();

        const int wm = (wv >> 1) * 32, wn = (wv & 1) * 32;
        f32x4 acc[2][2] = {};
        #pragma unroll
        for (int kf = 0; kf < 4; ++kf) {
            bf16x8 a[2], bb[2];
            #pragma unroll
            for (int fm = 0; fm < 2; ++fm)
                a[fm] = *(const bf16x8*)&Tst[(wm + fm * 16 + ln) * 136 + kf * 32 + q * 8];
            #pragma unroll
            for (int fn = 0; fn < 2; ++fn)
                bb[fn] = *(const bf16x8*)&Sst[(wn + fn * 16 + ln) * 136 + kf * 32 + q * 8];
            #pragma unroll
            for (int fm = 0; fm < 2; ++fm)
                #pragma unroll
                for (int fn = 0; fn < 2; ++fn)
                    acc[fm][fn] = __builtin_amdgcn_mfma_f32_16x16x32_bf16(a[fm], bb[fn], acc[fm][fn], 0, 0, 0);
        }
        float* pp = Mf + (size_t)b * 16384;
        #pragma unroll
        for (int fm = 0; fm < 2; ++fm)
            #pragma unroll
            for (int r = 0; r < 4; ++r) {
                int ee = e0 + wm + fm * 16 + q * 4 + r;
                #pragma unroll
                for (int fn = 0; fn < 2; ++fn) {
                    int dd = d0 + wn + fn * 16 + ln;
                    unsafeAtomicAdd(&pp[(size_t)ee * 128 + dd], acc[fm][fn][r]);
                }
            }
    }
}

// ---------------------------------------------------------------------------
// sim[row] = (1/S) <snb@M_b, tnb>_row via MFMA; M read fp32 from Mf (M^T).
// ---------------------------------------------------------------------------
__global__ __launch_bounds__(256) void simgemm_kernel(
    const unsigned short* __restrict__ snb, const unsigned short* __restrict__ tnb,
    const float* __restrict__ Mf, float* __restrict__ sim)
{
    __shared__ float red[64][2];
    const int tid = threadIdx.x, m0 = blockIdx.x * 64, b = m0 >> 11;
    const int wv = tid >> 6, lane = tid & 63, ln = lane & 15, q = lane >> 4;
    const int wm = (wv >> 1) * 32, wn = (wv & 1) * 64;

    f32x4 acc[2][4] = {};
    #pragma unroll
    for (int kf = 0; kf < 4; ++kf) {
        bf16x8 a[2], bb[4];
        #pragma unroll
        for (int fm = 0; fm < 2; ++fm)
            a[fm] = *(const bf16x8*)&snb[(size_t)(m0 + wm + fm * 16 + ln) * 128 + kf * 32 + q * 8];
        #pragma unroll
        for (int fn = 0; fn < 4; ++fn)
            bb[fn] = ldg_f32_b8(Mf + (size_t)b * 16384 + (size_t)(wn + fn * 16 + ln) * 128 + kf * 32 + q * 8);
        #pragma unroll
        for (int fm = 0; fm < 2; ++fm)
            #pragma unroll
            for (int fn = 0; fn < 4; ++fn)
                acc[fm][fn] = __builtin_amdgcn_mfma_f32_16x16x32_bf16(a[fm], bb[fn], acc[fm][fn], 0, 0, 0);
    }
    #pragma unroll
    for (int fm = 0; fm < 2; ++fm)
        #pragma unroll
        for (int r = 0; r < 4; ++r) {
            int rl = wm + fm * 16 + q * 4 + r;
            int row = m0 + rl;
            float s = 0.0f;
            #pragma unroll
            for (int fn = 0; fn < 4; ++fn) {
                int col = wn + fn * 16 + ln;
                s += acc[fm][fn][r] * b2f(tnb[(size_t)row * 128 + col]);
            }
            #pragma unroll
            for (int off = 1; off < 16; off <<= 1) s += __shfl_xor(s, off, 64);
            if (ln == 0) red[rl][wv & 1] = s;
        }
    __syncthreads();
    if (tid < 64) sim[m0 + tid] = (red[tid][0] + red[tid][1]) * (1.0f / (float)SS);
}

// ---------------------------------------------------------------------------
// Fused interaction block — weights pre-converted to bf16 (Wib/Wiob).
// ---------------------------------------------------------------------------
__global__ __launch_bounds__(256) void inter_block(
    const unsigned short* __restrict__ seb, const unsigned short* __restrict__ teb,
    const unsigned short* __restrict__ Wib,   // (384,128) bf16
    const float* __restrict__ b_int,
    const unsigned short* __restrict__ Wiob,  // (128,128) bf16
    const float* __restrict__ b_io,
    const float* __restrict__ sim, const float* __restrict__ x2,
    float* __restrict__ out)
{
    __shared__ unsigned short Qs[64 * 136];
    __shared__ unsigned short KVs[64 * 256];
    const int tid = threadIdx.x, s0 = blockIdx.x * 8;
    const int wv = tid >> 6, lane = tid & 63, ln = lane & 15, q = lane >> 4;
    const int wm = (wv >> 1) * 32, wn = (wv & 1) * 64;

    bf16x8 afr[4][2];
    #pragma unroll
    for (int kf = 0; kf < 4; ++kf)
        #pragma unroll
        for (int fm = 0; fm < 2; ++fm) {
            int rl = wm + fm * 16 + ln;
            size_t g = (size_t)(rl >> 3) * 2048 + s0 + (rl & 7);
            afr[kf][fm] = *(const bf16x8*)&seb[g * 128 + kf * 32 + q * 8];
        }

    #pragma unroll
    for (int p = 0; p < 3; ++p) {
        if (p == 1) {
            #pragma unroll
            for (int kf = 0; kf < 4; ++kf)
                #pragma unroll
                for (int fm = 0; fm < 2; ++fm) {
                    int rl = wm + fm * 16 + ln;
                    size_t g = (size_t)(rl >> 3) * 2048 + s0 + (rl & 7);
                    afr[kf][fm] = *(const bf16x8*)&teb[g * 128 + kf * 32 + q * 8];
                }
        }
        f32x4 acc[2][4] = {};
        #pragma unroll
        for (int kf = 0; kf < 4; ++kf) {
            bf16x8 b[4];
            #pragma unroll
            for (int fn = 0; fn < 4; ++fn)
                b[fn] = *(const bf16x8*)&Wib[(size_t)(p * 128 + wn + fn * 16 + ln) * 128 + kf * 32 + q * 8];
            #pragma unroll
            for (int fm = 0; fm < 2; ++fm)
                #pragma unroll
                for (int fn = 0; fn < 4; ++fn)
                    acc[fm][fn] = __builtin_amdgcn_mfma_f32_16x16x32_bf16(afr[kf][fm], b[fn], acc[fm][fn], 0, 0, 0);
        }
        #pragma unroll
        for (int fm = 0; fm < 2; ++fm)
            #pragma unroll
            for (int r = 0; r < 4; ++r) {
                int rl = wm + fm * 16 + q * 4 + r;
                #pragma unroll
                for (int fn = 0; fn < 4; ++fn) {
                    int col = wn + fn * 16 + ln;
                    unsigned short v = f2b(acc[fm][fn][r] + b_int[p * 128 + col]);
                    if (p == 0) Qs[rl * 136 + col] = v;
                    else        KVs[rl * 256 + (p - 1) * 128 + col] = v;
                }
            }
        __syncthreads();
    }

    #pragma unroll
    for (int tt = 0; tt < 2; ++tt) {
        int task = tid + tt * 256;
        int ss = task >> 6, h = (task >> 3) & 7, i = task & 7;
        int rq = i * 8 + ss;
        float qr[16];
        {
            uint4 q0 = *(const uint4*)&Qs[rq * 136 + h * 16];
            uint4 q1 = *(const uint4*)&Qs[rq * 136 + h * 16 + 8];
            const unsigned short* p0 = (const unsigned short*)&q0;
            const unsigned short* p1 = (const unsigned short*)&q1;
            #pragma unroll
            for (int c = 0; c < 8; ++c) { qr[c] = b2f(p0[c]); qr[8 + c] = b2f(p1[c]); }
        }
        float sc[8];
        #pragma unroll
        for (int j = 0; j < 8; ++j) {
            uint4 k0 = *(const uint4*)&KVs[(j * 8 + ss) * 256 + h * 16];
            uint4 k1 = *(const uint4*)&KVs[(j * 8 + ss) * 256 + h * 16 + 8];
            const unsigned short* kp0 = (const unsigned short*)&k0;
            const unsigned short* kp1 = (const unsigned short*)&k1;
            float s = 0.0f;
            #pragma unroll
            for (int c = 0; c < 8; ++c) {
                s = fmaf(qr[c], b2f(kp0[c]), s);
                s = fmaf(qr[8 + c], b2f(kp1[c]), s);
            }
            sc[j] = s * 0.25f;
        }
        float mx = -1e30f;
        #pragma unroll
        for (int j = 0; j < 8; ++j) mx = fmaxf(mx, sc[j]);
        float pe[8], se = 0.0f;
        #pragma unroll
        for (int j = 0; j < 8; ++j) { pe[j] = __expf(sc[j] - mx); se += pe[j]; }
        float inv = 1.0f / se;
        float o[16] = {};
        #pragma unroll
        for (int j = 0; j < 8; ++j) {
            uint4 v0 = *(const uint4*)&KVs[(j * 8 + ss) * 256 + 128 + h * 16];
            uint4 v1 = *(const uint4*)&KVs[(j * 8 + ss) * 256 + 128 + h * 16 + 8];
            const unsigned short* vp0 = (const unsigned short*)&v0;
            const unsigned short* vp1 = (const unsigned short*)&v1;
            #pragma unroll
            for (int c = 0; c < 8; ++c) {
                o[c]     += pe[j] * b2f(vp0[c]);
                o[8 + c] += pe[j] * b2f(vp1[c]);
            }
        }
        ushort4 w0 = (ushort4){f2b(o[0]*inv),  f2b(o[1]*inv),  f2b(o[2]*inv),  f2b(o[3]*inv)};
        ushort4 w1 = (ushort4){f2b(o[4]*inv),  f2b(o[5]*inv),  f2b(o[6]*inv),  f2b(o[7]*inv)};
        ushort4 w2 = (ushort4){f2b(o[8]*inv),  f2b(o[9]*inv),  f2b(o[10]*inv), f2b(o[11]*inv)};
        ushort4 w3 = (ushort4){f2b(o[12]*inv), f2b(o[13]*inv), f2b(o[14]*inv), f2b(o[15]*inv)};
        *(ushort4*)&Qs[rq * 136 + h * 16]      = w0;
        *(ushort4*)&Qs[rq * 136 + h * 16 + 4]  = w1;
        *(ushort4*)&Qs[rq * 136 + h * 16 + 8]  = w2;
        *(ushort4*)&Qs[rq * 136 + h * 16 + 12] = w3;
    }
    __syncthreads();

    f32x4 acc[2][4] = {};
    #pragma unroll
    for (int kf = 0; kf < 4; ++kf) {
        bf16x8 a[2], b[4];
        #pragma unroll
        for (int fm = 0; fm < 2; ++fm)
            a[fm] = *(const bf16x8*)&Qs[(wm + fm * 16 + ln) * 136 + kf * 32 + q * 8];
        #pragma unroll
        for (int fn = 0; fn < 4; ++fn)
            b[fn] = *(const bf16x8*)&Wiob[(size_t)(wn + fn * 16 + ln) * 128 + kf * 32 + q * 8];
        #pragma unroll
        for (int fm = 0; fm < 2; ++fm)
            #pragma unroll
            for (int fn = 0; fn < 4; ++fn)
                acc[fm][fn] = __builtin_amdgcn_mfma_f32_16x16x32_bf16(a[fm], b[fn], acc[fm][fn], 0, 0, 0);
    }
    #pragma unroll
    for (int fm = 0; fm < 2; ++fm)
        #pragma unroll
        for (int r = 0; r < 4; ++r) {
            int rl = wm + fm * 16 + q * 4 + r;
            size_t g = (size_t)(rl >> 3) * 2048 + s0 + (rl & 7);
            float sc = sim[g];
            #pragma unroll
            for (int fn = 0; fn < 4; ++fn) {
                int col = wn + fn * 16 + ln;
                out[g * 128 + col] = (acc[fm][fn][r] + b_io[col]) * sc + x2[g * 128 + col];
            }
        }
}

// ---------------------------------------------------------------------------
extern "C" void kernel_launch(void* const* d_in, const int* in_sizes, int n_in,
                              void* d_out, int out_size, void* d_ws, size_t ws_size,
                              hipStream_t stream)
{
    const float* x        = (const float*)d_in[0];
    const float* spatial  = (const float*)d_in[1];
    const float* temporal = (const float*)d_in[2];
    const float* lw_in_w  = (const float*)d_in[3];
    const float* lw_in_b  = (const float*)d_in[4];
    const float* lw_out_w = (const float*)d_in[5];
    const float* lw_out_b = (const float*)d_in[6];
    const float* spat_w   = (const float*)d_in[7];
    const float* spat_b   = (const float*)d_in[8];
    const float* temp_w   = (const float*)d_in[9];
    const float* temp_b   = (const float*)d_in[10];
    const float* int_in_w = (const float*)d_in[11];
    const float* int_in_b = (const float*)d_in[12];
    const float* int_out_w= (const float*)d_in[13];
    const float* int_out_b= (const float*)d_in[14];
    const float* ffn_b1   = (const float*)d_in[16];
    const float* ffn_b2   = (const float*)d_in[18];
    const float* ln1_g    = (const float*)d_in[19];
    const float* ln1_b    = (const float*)d_in[20];
    const float* ln2_g    = (const float*)d_in[21];
    const float* ln2_b    = (const float*)d_in[22];
    float* out = (float*)d_out;

    // ---- workspace layout (bytes) ----
    char* base = (char*)d_ws;
    float*          x1   = (float*)(base + 0);                   // 8,388,608
    unsigned short* x1b  = (unsigned short*)(base + 8388608);    // 4,194,304
    float*          x2   = (float*)(base + 12582912);            // 8,388,608
    unsigned short* snb  = (unsigned short*)(base + 20971520);   // 4,194,304
    unsigned short* tnb  = (unsigned short*)(base + 25165824);   // 4,194,304
    unsigned short* seb  = (unsigned short*)(base + 29360128);   // 4,194,304
    unsigned short* teb  = (unsigned short*)(base + 33554432);   // 4,194,304
    unsigned short* Wb   = (unsigned short*)(base + 37748736);   //   262,144
    unsigned short* Wib  = (unsigned short*)(base + 38010880);   //    98,304
    unsigned short* Wiob = (unsigned short*)(base + 38109184);   //    32,768
    float*          Mf   = (float*)(base + 38141952);            //   524,288
    float*          simb = (float*)(base + 38666240);            //    65,536
    unsigned short* Wlwb = (unsigned short*)(base + 38731776);   //   131,072
    unsigned short* Wstb = (unsigned short*)(base + 38862848);   //    65,536

    // 0: convert all weights to bf16 + zero Mf
    phase0<<<416, 256, 0, stream>>>(
        lw_in_w, lw_out_w, spat_w, temp_w,
        (const float*)d_in[15], (const float*)d_in[17], int_in_w, int_out_w,
        Wlwb, Wstb, Wb, Wib, Wiob, Mf);
    // 1: win_block (256) + stproj (512)
    phase1<<<768, 256, 0, stream>>>(
        x, Wlwb, lw_in_b, Wlwb + 49152, lw_out_b, ln1_g, ln1_b, x1, x1b,
        spatial, temporal, Wstb, Wstb + 16384, spat_b, temp_b,
        snb, tnb, seb, teb);
    // 2: ffn barrier-free (256) + atb split-K with fp32 atomics into Mf (512)
    phase2<<<768, 256, 0, stream>>>(
        x1b, x1, Wb, ffn_b1, ffn_b2, ln2_g, ln2_b, x2, snb, tnb, Mf);
    // 3: sim via MFMA (reads Mf fp32)
    simgemm_kernel<<<256, 256, 0, stream>>>(snb, tnb, Mf, simb);
    // 4: interaction block (bf16 weights)
    inter_block<<<256, 256, 0, stream>>>(
        seb, teb, Wib, int_in_b, Wiob, int_out_b, simb, x2, out);
}